// Round 10
// baseline (715.669 us; speedup 1.0000x reference)
//
#include <hip/hip_runtime.h>
#include <stdint.h>

// TWO chains per 256-thread block (256 blocks, 1 block/CU, 96 KB LDS).
// Every matmul round runs chain A then chain B back-to-back, then ONE
// __syncthreads covers both: half the barriers, and each barrier period has
// two independent load->MFMA->store streams (ILP hides ds_read latency).
//
// Each 64x64 matrix: bf16 planes in LDS, unpadded stride 64, XOR-swizzled:
//   element [r][c] at short-index  r*64 + (((c>>3) ^ (r&7))<<3) + (c&7)
//   R-plane: row-major (MFMA A-fragment = one b128)
//   T-plane: transposed (MFMA B-fragment = one b128)
#define PL 4096  // shorts per plane

typedef unsigned int u32;
typedef unsigned short u16;
typedef float f32x4 __attribute__((ext_vector_type(4)));
typedef short short8 __attribute__((ext_vector_type(8)));

__device__ __forceinline__ u32 prm(u32 a, u32 b, u32 s) {
  return __builtin_amdgcn_perm(a, b, s);
}
__device__ __forceinline__ u32 pk(float f0, float f1) {  // {bf16 f0, bf16 f1}
  return prm(__float_as_uint(f1), __float_as_uint(f0), 0x07060302u);
}
__device__ __forceinline__ float rlo(u32 w) { return __uint_as_float(w << 16); }
__device__ __forceinline__ float rhi(u32 w) {
  return __uint_as_float(w & 0xffff0000u);
}

// Per-thread invariant LDS short-offsets (4-wave 2x2 quadrant split).
struct O {
  int ra[2][2];  // A-frag read [ti][q]
  int rb[2][2];  // B-frag read [tj][q]
  int sT[2][2];  // T-plane store for primary product tile (ti,tj)
  int sR[2][2];  // R-plane store for mirror product tile (ti,tj)
  int prow[4];   // patch addr: sidx(r0+i, c0), 4-elem run
  int pcol[4];   // patch addr: sidx(c0+j, r0), 4-elem run
};

// B-fragment register cache (4 b128 loads of one round's B-operand).
struct BF {
  short8 b0[2], b1[2];
};

__device__ __forceinline__ BF loadB(const u16* __restrict__ BT, const O& o) {
  BF f;
#pragma unroll
  for (int t = 0; t < 2; ++t) {
    f.b0[t] = *(const short8*)(BT + o.rb[t][0]);
    f.b1[t] = *(const short8*)(BT + o.rb[t][1]);
  }
  return f;
}

// One chain's per-round compute, NO barrier (caller barriers after both
// chains). Wave wv owns quadrant as 2x2 16x16 tiles. Primary (a x b) ->
// C^T-contiguous -> T-plane; mirror (b x a) -> R-plane. WR/WT gate dead
// planes. TR: diagonal waves (0,3) also fold sum R.*T of the loaded
// fragments (= tr(A*B) = tr(m30) when A=R15,B=T15) into red[0..1].
template <bool WR, bool WT, bool TR = false>
__device__ __forceinline__ void mm_half(const u16* __restrict__ AR,
                                        const BF& bf, u16* __restrict__ CR,
                                        u16* __restrict__ CT, const O& o,
                                        float* red = nullptr) {
  short8 a0[2], a1[2];
#pragma unroll
  for (int t = 0; t < 2; ++t) {
    a0[t] = *(const short8*)(AR + o.ra[t][0]);
    a1[t] = *(const short8*)(AR + o.ra[t][1]);
  }
  if (TR) {
    const int tid = (int)threadIdx.x;
    const int wvv = tid >> 6;
    if (wvv == 0 || wvv == 3) {  // diagonal quadrants: frags element-aligned
      float part = 0.0f;
#pragma unroll
      for (int t = 0; t < 2; ++t) {
        const u32* ap0 = (const u32*)&a0[t];
        const u32* bp0 = (const u32*)&bf.b0[t];
        const u32* ap1 = (const u32*)&a1[t];
        const u32* bp1 = (const u32*)&bf.b1[t];
#pragma unroll
      for (int w = 0; w < 4; ++w) {
          part = fmaf(rlo(ap0[w]), rlo(bp0[w]), part);
          part = fmaf(rhi(ap0[w]), rhi(bp0[w]), part);
          part = fmaf(rlo(ap1[w]), rlo(bp1[w]), part);
          part = fmaf(rhi(ap1[w]), rhi(bp1[w]), part);
        }
      }
#pragma unroll
      for (int off = 1; off < 64; off <<= 1) part += __shfl_xor(part, off);
      if ((tid & 63) == 0) red[wvv == 0 ? 0 : 1] = part;
    }
  }
  const f32x4 Z = {0.0f, 0.0f, 0.0f, 0.0f};
#pragma unroll
  for (int ti = 0; ti < 2; ++ti)
#pragma unroll
    for (int tj = 0; tj < 2; ++tj) {
      if (WT) {
        f32x4 acc = __builtin_amdgcn_mfma_f32_16x16x32_bf16(a0[ti], bf.b0[tj],
                                                            Z, 0, 0, 0);
        acc = __builtin_amdgcn_mfma_f32_16x16x32_bf16(a1[ti], bf.b1[tj], acc,
                                                      0, 0, 0);
        *(uint2*)(CT + o.sT[ti][tj]) =
            make_uint2(pk(acc[0], acc[1]), pk(acc[2], acc[3]));
      }
      if (WR) {
        f32x4 acc = __builtin_amdgcn_mfma_f32_16x16x32_bf16(bf.b0[tj], a0[ti],
                                                            Z, 0, 0, 0);
        acc = __builtin_amdgcn_mfma_f32_16x16x32_bf16(bf.b1[tj], a1[ti], acc,
                                                      0, 0, 0);
        *(uint2*)(CR + o.sR[ti][tj]) =
            make_uint2(pk(acc[0], acc[1]), pk(acc[2], acc[3]));
      }
    }
}

// Per-chain state. Planes: 6 slots, 1-periodic schedule (verified R8/R9);
// invariant entering each iter: PA=R15, PB=T15, PC=T3 of current x.
struct Chain {
  u16 *PA, *PB, *PC, *PD, *PE, *PF;
  float* red;  // 2 floats
  float x[4][4], sc[4][4];
  float alpha;
  BF cC;  // register cache of T3's B-fragments (c3 -> c5 -> next f3)
};

__global__ __launch_bounds__(256, 1) void dag_iter_kernel(
    const float* __restrict__ adj, float* __restrict__ out) {
  __shared__ __align__(16) u16 BUF[12 * PL];
  __shared__ float red[4];

  const int tid = (int)threadIdx.x;
  const int lane = tid & 63;
  const int wv = tid >> 6;
  const int rh4 = (wv >> 1) << 1;
  const int ch4 = (wv & 1) << 1;
  const int l15 = lane & 15;
  const int grp = lane >> 4;
  const int l7 = l15 & 7;
  const int r0 = (tid & 15) << 2;
  const int c0 = (tid >> 4) << 2;

  O o;
#pragma unroll
  for (int q = 0; q < 2; ++q) {
    const int koff = (((q << 2) + grp) ^ l7) << 3;
#pragma unroll
    for (int t = 0; t < 2; ++t) {
      o.ra[t][q] = ((rh4 + t) * 16 + l15) * 64 + koff;
      o.rb[t][q] = ((ch4 + t) * 16 + l15) * 64 + koff;
    }
  }
#pragma unroll
  for (int ti = 0; ti < 2; ++ti)
#pragma unroll
    for (int tj = 0; tj < 2; ++tj) {
      const int a = rh4 + ti;
      const int b = ch4 + tj;
      o.sT[ti][tj] = (16 * b + l15) * 64 +
                     (((2 * a + (grp >> 1)) ^ l7) << 3) + ((grp & 1) << 2);
      o.sR[ti][tj] = (16 * a + l15) * 64 +
                     (((2 * b + (grp >> 1)) ^ l7) << 3) + ((grp & 1) << 2);
    }
#pragma unroll
  for (int i = 0; i < 4; ++i) {
    o.prow[i] =
        (r0 + i) * 64 + ((((c0 >> 3) ^ ((r0 + i) & 7))) << 3) + (c0 & 7);
    o.pcol[i] =
        (c0 + i) * 64 + ((((r0 >> 3) ^ ((c0 + i) & 7))) << 3) + (r0 & 7);
  }

  Chain ch[2];
#pragma unroll
  for (int k = 0; k < 2; ++k) {
    u16* base = BUF + k * 6 * PL;
    ch[k].PA = base;
    ch[k].PB = base + PL;
    ch[k].PC = base + 2 * PL;
    ch[k].PD = base + 3 * PL;
    ch[k].PE = base + 4 * PL;
    ch[k].PF = base + 5 * PL;
    ch[k].red = &red[2 * k];
    const float* src = adj + ((size_t)blockIdx.x * 2 + k) * 4096;
#pragma unroll
    for (int i = 0; i < 4; ++i) {
      f32x4 v = *(const f32x4*)(src + (r0 + i) * 64 + c0);
#pragma unroll
      for (int j = 0; j < 4; ++j) {
        ch[k].x[i][j] = v[j];
        ch[k].sc[i][j] = (v[j] > 0.5f) ? v[j] : 0.0f;
      }
    }
    ch[k].alpha = 0.0f;
  }

  auto prox = [&](Chain& C, float til[4][4]) {
#pragma unroll
    for (int i = 0; i < 4; ++i)
#pragma unroll
      for (int j = 0; j < 4; ++j) {
        float ax = fabsf(til[i][j]) - 2e-5f;
        float nx = ax > 0.0f ? ax : 0.0f;
        C.x[i][j] = nx > 1.0f ? 1.0f : nx;
      }
  };
  auto stage1 = [&](Chain& C) {  // m = I + x.*x/64 -> PE (R), PF (T); no bar
    float m[4][4];
#pragma unroll
    for (int i = 0; i < 4; ++i)
#pragma unroll
      for (int j = 0; j < 4; ++j)
        m[i][j] = fmaf(C.x[i][j] * C.x[i][j], 0.015625f,
                       (r0 + i == c0 + j) ? 1.0f : 0.0f);
#pragma unroll
    for (int i = 0; i < 4; ++i)
      *(uint2*)(C.PE + o.prow[i]) =
          make_uint2(pk(m[i][0], m[i][1]), pk(m[i][2], m[i][3]));
#pragma unroll
    for (int j = 0; j < 4; ++j)
      *(uint2*)(C.PF + o.pcol[j]) =
          make_uint2(pk(m[0][j], m[1][j]), pk(m[2][j], m[3][j]));
  };
  auto gradprox = [&](Chain& C) {  // alpha from red (tr(m30)); T63 in PD
    float tr = C.red[0] + C.red[1];
    C.alpha = fmaf(0.01f, tr * 0.015625f - 1.0f, C.alpha);
    const float a2 = C.alpha * 0.03125f;  // 2*alpha/64
    float til[4][4];
#pragma unroll
    for (int i = 0; i < 4; ++i) {
      uint2 w = *(const uint2*)(C.PD + o.prow[i]);
      float pt[4] = {rlo(w.x), rhi(w.x), rlo(w.y), rhi(w.y)};
#pragma unroll
      for (int j = 0; j < 4; ++j) {
        float g = fmaf(a2 * C.x[i][j], pt[j], -C.sc[i][j]);
        til[i][j] = fmaf(-0.01f, g, C.x[i][j]);
      }
    }
    prox(C, til);
  };

  auto front2 = [&]() {
    {  // f1: m30 = m15^2 -> (PD,PE), + free trace
      BF ba = loadB(ch[0].PB, o);
      BF bb = loadB(ch[1].PB, o);
      mm_half<true, true, true>(ch[0].PA, ba, ch[0].PD, ch[0].PE, o,
                                ch[0].red);
      mm_half<true, true, true>(ch[1].PA, bb, ch[1].PD, ch[1].PE, o,
                                ch[1].red);
      __syncthreads();
    }
    {  // f2: m60 = m30^2 -> PF [R only]
      BF ba = loadB(ch[0].PE, o);
      BF bb = loadB(ch[1].PE, o);
      mm_half<true, false>(ch[0].PD, ba, ch[0].PF, ch[0].PF, o);
      mm_half<true, false>(ch[1].PD, bb, ch[1].PF, ch[1].PF, o);
      __syncthreads();
    }
    {  // f3: m63 = m60*m3 -> PD [T only]; B from cC register cache
      mm_half<false, true>(ch[0].PF, ch[0].cC, ch[0].PD, ch[0].PD, o);
      mm_half<false, true>(ch[1].PF, ch[1].cC, ch[1].PD, ch[1].PD, o);
      __syncthreads();
    }
  };
  auto chain52 = [&]() {  // sources: PE=R(m), PF=T(m) per chain
    BF fa = loadB(ch[0].PF, o);
    BF fb = loadB(ch[1].PF, o);
    // c1: m2 = m*m -> PD [R only]
    mm_half<true, false>(ch[0].PE, fa, ch[0].PD, ch[0].PD, o);
    mm_half<true, false>(ch[1].PE, fb, ch[1].PD, ch[1].PD, o);
    __syncthreads();
    // c2: m3 = m2*m -> (PE=R3, PC=T3); B reused from fa/fb
    mm_half<true, true>(ch[0].PD, fa, ch[0].PE, ch[0].PC, o);
    mm_half<true, true>(ch[1].PD, fb, ch[1].PE, ch[1].PC, o);
    __syncthreads();
    // c3: m6 = m3^2 -> (PD,PF); load+persist cC = T3
    ch[0].cC = loadB(ch[0].PC, o);
    ch[1].cC = loadB(ch[1].PC, o);
    mm_half<true, true>(ch[0].PE, ch[0].cC, ch[0].PD, ch[0].PF, o);
    mm_half<true, true>(ch[1].PE, ch[1].cC, ch[1].PD, ch[1].PF, o);
    __syncthreads();
    // c4: m12 = m6^2 -> PE [R only]
    {
      BF ga = loadB(ch[0].PF, o);
      BF gb = loadB(ch[1].PF, o);
      mm_half<true, false>(ch[0].PD, ga, ch[0].PE, ch[0].PE, o);
      mm_half<true, false>(ch[1].PD, gb, ch[1].PE, ch[1].PE, o);
      __syncthreads();
    }
    // c5: m15 = m12*m3 -> (PA,PB); B = cC
    mm_half<true, true>(ch[0].PE, ch[0].cC, ch[0].PA, ch[0].PB, o);
    mm_half<true, true>(ch[1].PE, ch[1].cC, ch[1].PA, ch[1].PB, o);
    __syncthreads();
  };

  // ---- iteration 0: alpha == 0 -> grad = -scores ----
#pragma unroll
  for (int k = 0; k < 2; ++k) {
    float til[4][4];
#pragma unroll
    for (int i = 0; i < 4; ++i)
#pragma unroll
      for (int j = 0; j < 4; ++j)
        til[i][j] = fmaf(0.01f, ch[k].sc[i][j], ch[k].x[i][j]);
    prox(ch[k], til);
    stage1(ch[k]);
  }
  __syncthreads();
  chain52();
  // ---- iterations 1..48 ----
  for (int it = 0; it < 48; ++it) {
    front2();
    gradprox(ch[0]);
    gradprox(ch[1]);
    stage1(ch[0]);
    stage1(ch[1]);
    __syncthreads();
    chain52();
  }
  // ---- iteration 49: no trailing stage/chain ----
  front2();
  gradprox(ch[0]);
  gradprox(ch[1]);

#pragma unroll
  for (int k = 0; k < 2; ++k) {
    float* dst = out + ((size_t)blockIdx.x * 2 + k) * 4096;
#pragma unroll
    for (int i = 0; i < 4; ++i) {
      f32x4 v;
#pragma unroll
      for (int j = 0; j < 4; ++j)
        v[j] = (ch[k].x[i][j] > 0.5f) ? ch[k].x[i][j] : 0.0f;
      *(f32x4*)(dst + (r0 + i) * 64 + c0) = v;
    }
  }
}

extern "C" void kernel_launch(void* const* d_in, const int* in_sizes, int n_in,
                              void* d_out, int out_size, void* d_ws,
                              size_t ws_size, hipStream_t stream) {
  const float* adj = (const float*)d_in[0];
  float* out = (float*)d_out;
  const int nbatch = in_sizes[0] / 4096;  // 512
  dag_iter_kernel<<<nbatch / 2, 256, 0, stream>>>(adj, out);
}

// Round 11
// 373.488 us; speedup vs baseline: 1.9162x; 1.9162x over previous
//
#include <hip/hip_runtime.h>
#include <stdint.h>

// TWO chains per 256-thread block (256 blocks, 1 block/CU, 96 KB LDS).
// Every matmul round: issue BOTH chains' LDS fragment loads back-to-back,
// then both MFMA+store streams, then ONE __syncthreads. Cross-chain ILP
// hides ds_read latency; barrier count per 2 chains halves vs R9.
// All state in flat locals (R10's struct-array + lambda captures caused
// scratch spill: WRITE_SIZE 765 MB).
//
// Each 64x64 matrix: bf16 planes in LDS, unpadded stride 64, XOR-swizzled:
//   element [r][c] at short-index  r*64 + (((c>>3) ^ (r&7))<<3) + (c&7)
//   R-plane: row-major (MFMA A-fragment = one b128)
//   T-plane: transposed (MFMA B-fragment = one b128)
#define PL 4096  // shorts per plane

typedef unsigned int u32;
typedef unsigned short u16;
typedef float f32x4 __attribute__((ext_vector_type(4)));
typedef short short8 __attribute__((ext_vector_type(8)));

__device__ __forceinline__ u32 prm(u32 a, u32 b, u32 s) {
  return __builtin_amdgcn_perm(a, b, s);
}
__device__ __forceinline__ u32 pk(float f0, float f1) {  // {bf16 f0, bf16 f1}
  return prm(__float_as_uint(f1), __float_as_uint(f0), 0x07060302u);
}
__device__ __forceinline__ float rlo(u32 w) { return __uint_as_float(w << 16); }
__device__ __forceinline__ float rhi(u32 w) {
  return __uint_as_float(w & 0xffff0000u);
}

// Per-thread invariant LDS short-offsets (4-wave 2x2 quadrant split).
struct O {
  int ra[2][2];  // A-frag read [ti][q]
  int rb[2][2];  // B-frag read [tj][q]
  int sT[2][2];  // T-plane store for primary product tile (ti,tj)
  int sR[2][2];  // R-plane store for mirror product tile (ti,tj)
  int prow[4];   // patch addr: sidx(r0+i, c0), 4-elem run
  int pcol[4];   // patch addr: sidx(c0+j, r0), 4-elem run
};

// One matmul round for BOTH chains, one trailing barrier.
// Per chain: primary (a x b) -> C^T-contiguous -> T-plane; mirror (b x a)
// -> R-plane. WR/WT gate dead planes. TR: diagonal waves (0,3) fold
// sum R.*T of loaded fragments (= tr(A*B) = tr(m30) when A=R15,B=T15) into
// red[0..1] (chain0) / red[2..3] (chain1).
template <bool WR, bool WT, bool TR = false>
__device__ __forceinline__ void mm_pair(
    const u16* __restrict__ AR0, const u16* __restrict__ BT0,
    u16* __restrict__ CR0, u16* __restrict__ CT0, const u16* __restrict__ AR1,
    const u16* __restrict__ BT1, u16* __restrict__ CR1,
    u16* __restrict__ CT1, const O& o, float* red) {
  short8 a0A[2], a1A[2], b0A[2], b1A[2];
  short8 a0B[2], a1B[2], b0B[2], b1B[2];
#pragma unroll
  for (int t = 0; t < 2; ++t) {
    a0A[t] = *(const short8*)(AR0 + o.ra[t][0]);
    a1A[t] = *(const short8*)(AR0 + o.ra[t][1]);
    b0A[t] = *(const short8*)(BT0 + o.rb[t][0]);
    b1A[t] = *(const short8*)(BT0 + o.rb[t][1]);
    a0B[t] = *(const short8*)(AR1 + o.ra[t][0]);
    a1B[t] = *(const short8*)(AR1 + o.ra[t][1]);
    b0B[t] = *(const short8*)(BT1 + o.rb[t][0]);
    b1B[t] = *(const short8*)(BT1 + o.rb[t][1]);
  }
  if (TR) {
    const int tid = (int)threadIdx.x;
    const int wvv = tid >> 6;
    if (wvv == 0 || wvv == 3) {  // diagonal quadrants: frags element-aligned
      float p0 = 0.0f, p1 = 0.0f;
#pragma unroll
      for (int t = 0; t < 2; ++t) {
        const u32* xa = (const u32*)&a0A[t];
        const u32* xb = (const u32*)&b0A[t];
        const u32* ya = (const u32*)&a1A[t];
        const u32* yb = (const u32*)&b1A[t];
        const u32* za = (const u32*)&a0B[t];
        const u32* zb = (const u32*)&b0B[t];
        const u32* wa = (const u32*)&a1B[t];
        const u32* wb = (const u32*)&b1B[t];
#pragma unroll
        for (int w = 0; w < 4; ++w) {
          p0 = fmaf(rlo(xa[w]), rlo(xb[w]), p0);
          p0 = fmaf(rhi(xa[w]), rhi(xb[w]), p0);
          p0 = fmaf(rlo(ya[w]), rlo(yb[w]), p0);
          p0 = fmaf(rhi(ya[w]), rhi(yb[w]), p0);
          p1 = fmaf(rlo(za[w]), rlo(zb[w]), p1);
          p1 = fmaf(rhi(za[w]), rhi(zb[w]), p1);
          p1 = fmaf(rlo(wa[w]), rlo(wb[w]), p1);
          p1 = fmaf(rhi(wa[w]), rhi(wb[w]), p1);
        }
      }
#pragma unroll
      for (int off = 1; off < 64; off <<= 1) {
        p0 += __shfl_xor(p0, off);
        p1 += __shfl_xor(p1, off);
      }
      if ((tid & 63) == 0) {
        red[wvv == 0 ? 0 : 1] = p0;
        red[wvv == 0 ? 2 : 3] = p1;
      }
    }
  }
  const f32x4 Z = {0.0f, 0.0f, 0.0f, 0.0f};
#pragma unroll
  for (int ti = 0; ti < 2; ++ti)
#pragma unroll
    for (int tj = 0; tj < 2; ++tj) {
      if (WT) {
        f32x4 acc = __builtin_amdgcn_mfma_f32_16x16x32_bf16(a0A[ti], b0A[tj],
                                                            Z, 0, 0, 0);
        acc = __builtin_amdgcn_mfma_f32_16x16x32_bf16(a1A[ti], b1A[tj], acc,
                                                      0, 0, 0);
        *(uint2*)(CT0 + o.sT[ti][tj]) =
            make_uint2(pk(acc[0], acc[1]), pk(acc[2], acc[3]));
        f32x4 acd = __builtin_amdgcn_mfma_f32_16x16x32_bf16(a0B[ti], b0B[tj],
                                                            Z, 0, 0, 0);
        acd = __builtin_amdgcn_mfma_f32_16x16x32_bf16(a1B[ti], b1B[tj], acd,
                                                      0, 0, 0);
        *(uint2*)(CT1 + o.sT[ti][tj]) =
            make_uint2(pk(acd[0], acd[1]), pk(acd[2], acd[3]));
      }
      if (WR) {
        f32x4 acc = __builtin_amdgcn_mfma_f32_16x16x32_bf16(b0A[tj], a0A[ti],
                                                            Z, 0, 0, 0);
        acc = __builtin_amdgcn_mfma_f32_16x16x32_bf16(b1A[tj], a1A[ti], acc,
                                                      0, 0, 0);
        *(uint2*)(CR0 + o.sR[ti][tj]) =
            make_uint2(pk(acc[0], acc[1]), pk(acc[2], acc[3]));
        f32x4 acd = __builtin_amdgcn_mfma_f32_16x16x32_bf16(b0B[tj], a0B[ti],
                                                            Z, 0, 0, 0);
        acd = __builtin_amdgcn_mfma_f32_16x16x32_bf16(b1B[tj], a1B[ti], acd,
                                                      0, 0, 0);
        *(uint2*)(CR1 + o.sR[ti][tj]) =
            make_uint2(pk(acd[0], acd[1]), pk(acd[2], acd[3]));
      }
    }
  __syncthreads();
}

__device__ __forceinline__ void proxup(float (&x)[4][4],
                                       const float (&til)[4][4]) {
#pragma unroll
  for (int i = 0; i < 4; ++i)
#pragma unroll
    for (int j = 0; j < 4; ++j) {
      float ax = fabsf(til[i][j]) - 2e-5f;
      float nx = ax > 0.0f ? ax : 0.0f;
      x[i][j] = nx > 1.0f ? 1.0f : nx;
    }
}

// stage m = I + x.*x/64 into R-plane PR and T-plane PT (no barrier)
__device__ __forceinline__ void stage1(const float (&x)[4][4],
                                       u16* __restrict__ PR,
                                       u16* __restrict__ PT, const O& o,
                                       int r0, int c0) {
  float m[4][4];
#pragma unroll
  for (int i = 0; i < 4; ++i)
#pragma unroll
    for (int j = 0; j < 4; ++j)
      m[i][j] = fmaf(x[i][j] * x[i][j], 0.015625f,
                     (r0 + i == c0 + j) ? 1.0f : 0.0f);
#pragma unroll
  for (int i = 0; i < 4; ++i)
    *(uint2*)(PR + o.prow[i]) =
        make_uint2(pk(m[i][0], m[i][1]), pk(m[i][2], m[i][3]));
#pragma unroll
  for (int j = 0; j < 4; ++j)
    *(uint2*)(PT + o.pcol[j]) =
        make_uint2(pk(m[0][j], m[1][j]), pk(m[2][j], m[3][j]));
}

// gradient + prox; T63 in PD, trace in red2[0..1]
__device__ __forceinline__ void gradprox(float (&x)[4][4],
                                         const float (&sc)[4][4], float& alpha,
                                         const u16* __restrict__ PD,
                                         const float* red2, const O& o) {
  float tr = red2[0] + red2[1];
  alpha = fmaf(0.01f, tr * 0.015625f - 1.0f, alpha);
  const float a2 = alpha * 0.03125f;  // 2*alpha/64
  float til[4][4];
#pragma unroll
  for (int i = 0; i < 4; ++i) {
    uint2 w = *(const uint2*)(PD + o.prow[i]);
    float pt[4] = {rlo(w.x), rhi(w.x), rlo(w.y), rhi(w.y)};
#pragma unroll
    for (int j = 0; j < 4; ++j) {
      float g = fmaf(a2 * x[i][j], pt[j], -sc[i][j]);
      til[i][j] = fmaf(-0.01f, g, x[i][j]);
    }
  }
  proxup(x, til);
}

// 1-periodic 6-slot schedule per chain (verified R8/R9), invariant entering
// each iter: PA=R15, PB=T15, PC=T3 of current x.
//   f1 m30:(PA,PB)->(PD,PE) [+trace]  f2 m60:(PD,PE)->PF [R]
//   f3 m63:(PF,PC)->PD [T]
//   gradprox; stage->(PE,PF); c1 m2:(PE,PF)->PD [R]
//   c2 m3:(PD,PF)->(PE,PC)  c3 m6:(PE,PC)->(PD,PF)  c4 m12:(PD,PF)->PE [R]
//   c5 m15:(PE,PC)->(PA,PB)
__global__ __launch_bounds__(256, 1) void dag_iter_kernel(
    const float* __restrict__ adj, float* __restrict__ out) {
  __shared__ __align__(16) u16 BUF[12 * PL];
  __shared__ float red[4];
  u16* A0 = BUF;
  u16* B0 = BUF + PL;
  u16* C0 = BUF + 2 * PL;
  u16* D0 = BUF + 3 * PL;
  u16* E0 = BUF + 4 * PL;
  u16* F0 = BUF + 5 * PL;
  u16* A1 = BUF + 6 * PL;
  u16* B1 = BUF + 7 * PL;
  u16* C1 = BUF + 8 * PL;
  u16* D1 = BUF + 9 * PL;
  u16* E1 = BUF + 10 * PL;
  u16* F1 = BUF + 11 * PL;

  const int tid = (int)threadIdx.x;
  const int lane = tid & 63;
  const int wv = tid >> 6;
  const int rh4 = (wv >> 1) << 1;
  const int ch4 = (wv & 1) << 1;
  const int l15 = lane & 15;
  const int grp = lane >> 4;
  const int l7 = l15 & 7;
  const int r0 = (tid & 15) << 2;
  const int c0 = (tid >> 4) << 2;

  O o;
#pragma unroll
  for (int q = 0; q < 2; ++q) {
    const int koff = (((q << 2) + grp) ^ l7) << 3;
#pragma unroll
    for (int t = 0; t < 2; ++t) {
      o.ra[t][q] = ((rh4 + t) * 16 + l15) * 64 + koff;
      o.rb[t][q] = ((ch4 + t) * 16 + l15) * 64 + koff;
    }
  }
#pragma unroll
  for (int ti = 0; ti < 2; ++ti)
#pragma unroll
    for (int tj = 0; tj < 2; ++tj) {
      const int a = rh4 + ti;
      const int b = ch4 + tj;
      o.sT[ti][tj] = (16 * b + l15) * 64 +
                     (((2 * a + (grp >> 1)) ^ l7) << 3) + ((grp & 1) << 2);
      o.sR[ti][tj] = (16 * a + l15) * 64 +
                     (((2 * b + (grp >> 1)) ^ l7) << 3) + ((grp & 1) << 2);
    }
#pragma unroll
  for (int i = 0; i < 4; ++i) {
    o.prow[i] =
        (r0 + i) * 64 + ((((c0 >> 3) ^ ((r0 + i) & 7))) << 3) + (c0 & 7);
    o.pcol[i] =
        (c0 + i) * 64 + ((((r0 >> 3) ^ ((c0 + i) & 7))) << 3) + (r0 & 7);
  }

  float x0[4][4], sc0[4][4], x1[4][4], sc1[4][4];
  {
    const float* s0 = adj + ((size_t)blockIdx.x * 2) * 4096;
    const float* s1 = s0 + 4096;
#pragma unroll
    for (int i = 0; i < 4; ++i) {
      f32x4 v = *(const f32x4*)(s0 + (r0 + i) * 64 + c0);
      f32x4 w = *(const f32x4*)(s1 + (r0 + i) * 64 + c0);
#pragma unroll
      for (int j = 0; j < 4; ++j) {
        x0[i][j] = v[j];
        sc0[i][j] = (v[j] > 0.5f) ? v[j] : 0.0f;
        x1[i][j] = w[j];
        sc1[i][j] = (w[j] > 0.5f) ? w[j] : 0.0f;
      }
    }
  }
  float alpha0 = 0.0f, alpha1 = 0.0f;

  // ---- iteration 0: alpha == 0 -> grad = -scores ----
  {
    float t0[4][4], t1[4][4];
#pragma unroll
    for (int i = 0; i < 4; ++i)
#pragma unroll
      for (int j = 0; j < 4; ++j) {
        t0[i][j] = fmaf(0.01f, sc0[i][j], x0[i][j]);
        t1[i][j] = fmaf(0.01f, sc1[i][j], x1[i][j]);
      }
    proxup(x0, t0);
    proxup(x1, t1);
    stage1(x0, E0, F0, o, r0, c0);
    stage1(x1, E1, F1, o, r0, c0);
    __syncthreads();
    mm_pair<true, false>(E0, F0, D0, D0, E1, F1, D1, D1, o, red);  // c1
    mm_pair<true, true>(D0, F0, E0, C0, D1, F1, E1, C1, o, red);   // c2
    mm_pair<true, true>(E0, C0, D0, F0, E1, C1, D1, F1, o, red);   // c3
    mm_pair<true, false>(D0, F0, E0, E0, D1, F1, E1, E1, o, red);  // c4
    mm_pair<true, true>(E0, C0, A0, B0, E1, C1, A1, B1, o, red);   // c5
  }
  // ---- iterations 1..49 ----
  for (int it = 0; it < 49; ++it) {
    mm_pair<true, true, true>(A0, B0, D0, E0, A1, B1, D1, E1, o, red);  // f1
    mm_pair<true, false>(D0, E0, F0, F0, D1, E1, F1, F1, o, red);       // f2
    mm_pair<false, true>(F0, C0, D0, D0, F1, C1, D1, D1, o, red);       // f3
    gradprox(x0, sc0, alpha0, D0, &red[0], o);
    gradprox(x1, sc1, alpha1, D1, &red[2], o);
    if (it == 48) break;  // last iteration: no trailing stage/chain
    stage1(x0, E0, F0, o, r0, c0);
    stage1(x1, E1, F1, o, r0, c0);
    __syncthreads();
    mm_pair<true, false>(E0, F0, D0, D0, E1, F1, D1, D1, o, red);  // c1
    mm_pair<true, true>(D0, F0, E0, C0, D1, F1, E1, C1, o, red);   // c2
    mm_pair<true, true>(E0, C0, D0, F0, E1, C1, D1, F1, o, red);   // c3
    mm_pair<true, false>(D0, F0, E0, E0, D1, F1, E1, E1, o, red);  // c4
    mm_pair<true, true>(E0, C0, A0, B0, E1, C1, A1, B1, o, red);   // c5
  }

  {
    float* d0 = out + ((size_t)blockIdx.x * 2) * 4096;
    float* d1 = d0 + 4096;
#pragma unroll
    for (int i = 0; i < 4; ++i) {
      f32x4 v, w;
#pragma unroll
      for (int j = 0; j < 4; ++j) {
        v[j] = (x0[i][j] > 0.5f) ? x0[i][j] : 0.0f;
        w[j] = (x1[i][j] > 0.5f) ? x1[i][j] : 0.0f;
      }
      *(f32x4*)(d0 + (r0 + i) * 64 + c0) = v;
      *(f32x4*)(d1 + (r0 + i) * 64 + c0) = w;
    }
  }
}

extern "C" void kernel_launch(void* const* d_in, const int* in_sizes, int n_in,
                              void* d_out, int out_size, void* d_ws,
                              size_t ws_size, hipStream_t stream) {
  const float* adj = (const float*)d_in[0];
  float* out = (float*)d_out;
  const int nbatch = in_sizes[0] / 4096;  // 512
  dag_iter_kernel<<<nbatch / 2, 256, 0, stream>>>(adj, out);
}

// Round 12
// 320.299 us; speedup vs baseline: 2.2344x; 1.1661x over previous
//
#include <hip/hip_runtime.h>
#include <stdint.h>

// One chain per 256-thread block (512 blocks, 2/CU de-phased, 8 waves/CU).
// Depth-6 exponent DAG per iteration (10 matmuls, 6 barrier periods):
//   t1: m2 | t2: m3,m4 | t3: m7,m8 | t4: m15,m16 | t5: m31,m32 (+trace)
//   t6: m63        where tr(m30) = tr(m15*m15) = sum R15 .* T15 elementwise.
// vs R9's depth-8 chain (8 matmuls, 8 periods + stage): 9 -> 7 periods/iter.
// Dual-mm periods share B-fragments -> total fragment reads unchanged.
//
// Each 64x64 matrix: bf16 planes in LDS, unpadded stride 64, XOR-swizzled:
//   element [r][c] at short-index  r*64 + (((c>>3) ^ (r&7))<<3) + (c&7)
//   R-plane: row-major (MFMA A-fragment = one b128)
//   T-plane: transposed (MFMA B-fragment = one b128)
// 7 plane slots S0..S6, 1-periodic allocation (verified liveness):
//   p0: stage Rm->S0, Tm->S1 (T63 read from S2)
//   t1: m2:(S0,S1)->R2=S3,T2=S4      t2: m3:(S3,S1)->R3=S2,
//       m4:(S3,S4)->R4=S5,T4=S6      t3: m7:(S2,S6)->R7=S0,
//       m8:(S5,S6)->R8=S3,T8=S4      t4: m15:(S0,S4)->R15=S1,T15=S2,
//       m16:(S3,S4)->R16=S5,T16=S6   t5: m31:(S1,S6)->R31=S0,
//       m32:(S5,S6)->T32=S3, trace(S1,S2)->red
//   t6: m63:(S0,S3)->T63=S2
#define PL 4096  // shorts per plane

typedef unsigned int u32;
typedef unsigned short u16;
typedef float f32x4 __attribute__((ext_vector_type(4)));
typedef short short8 __attribute__((ext_vector_type(8)));

__device__ __forceinline__ u32 prm(u32 a, u32 b, u32 s) {
  return __builtin_amdgcn_perm(a, b, s);
}
__device__ __forceinline__ u32 pk(float f0, float f1) {  // {bf16 f0, bf16 f1}
  return prm(__float_as_uint(f1), __float_as_uint(f0), 0x07060302u);
}
__device__ __forceinline__ float rlo(u32 w) { return __uint_as_float(w << 16); }
__device__ __forceinline__ float rhi(u32 w) {
  return __uint_as_float(w & 0xffff0000u);
}

// Per-thread invariant LDS short-offsets (4-wave 2x2 quadrant split).
struct O {
  int ra[2][2];  // A-frag read [ti][q]
  int rb[2][2];  // B-frag read [tj][q]
  int sT[2][2];  // T-plane store for primary product tile (ti,tj)
  int sR[2][2];  // R-plane store for mirror product tile (ti,tj)
  int prow[4];   // patch addr: sidx(r0+i, c0), 4-elem run
  int pcol[4];   // patch addr: sidx(c0+j, r0), 4-elem run
};

struct FR {  // A-operand fragments of one plane (this wave's row quadrant)
  short8 f[2][2];
};
struct FB {  // B-operand fragments of one plane (this wave's col quadrant)
  short8 f[2][2];
};

__device__ __forceinline__ FR loadR(const u16* __restrict__ P, const O& o) {
  FR r;
#pragma unroll
  for (int t = 0; t < 2; ++t)
#pragma unroll
    for (int q = 0; q < 2; ++q) r.f[t][q] = *(const short8*)(P + o.ra[t][q]);
  return r;
}
__device__ __forceinline__ FB loadT(const u16* __restrict__ P, const O& o) {
  FB r;
#pragma unroll
  for (int t = 0; t < 2; ++t)
#pragma unroll
    for (int q = 0; q < 2; ++q) r.f[t][q] = *(const short8*)(P + o.rb[t][q]);
  return r;
}

// primary product A x B -> D is C^T-contiguous -> T-plane of C
__device__ __forceinline__ void prodT(const FR& a, const FB& b,
                                      u16* __restrict__ CT, const O& o) {
  const f32x4 Z = {0.0f, 0.0f, 0.0f, 0.0f};
#pragma unroll
  for (int ti = 0; ti < 2; ++ti)
#pragma unroll
    for (int tj = 0; tj < 2; ++tj) {
      f32x4 acc = __builtin_amdgcn_mfma_f32_16x16x32_bf16(a.f[ti][0],
                                                          b.f[tj][0], Z, 0, 0,
                                                          0);
      acc = __builtin_amdgcn_mfma_f32_16x16x32_bf16(a.f[ti][1], b.f[tj][1],
                                                    acc, 0, 0, 0);
      *(uint2*)(CT + o.sT[ti][tj]) =
          make_uint2(pk(acc[0], acc[1]), pk(acc[2], acc[3]));
    }
}
// mirror product B x A (= C^T as a product) -> C-contiguous -> R-plane of C
__device__ __forceinline__ void prodR(const FR& a, const FB& b,
                                      u16* __restrict__ CR, const O& o) {
  const f32x4 Z = {0.0f, 0.0f, 0.0f, 0.0f};
#pragma unroll
  for (int ti = 0; ti < 2; ++ti)
#pragma unroll
    for (int tj = 0; tj < 2; ++tj) {
      f32x4 acc = __builtin_amdgcn_mfma_f32_16x16x32_bf16(b.f[tj][0],
                                                          a.f[ti][0], Z, 0, 0,
                                                          0);
      acc = __builtin_amdgcn_mfma_f32_16x16x32_bf16(b.f[tj][1], a.f[ti][1],
                                                    acc, 0, 0, 0);
      *(uint2*)(CR + o.sR[ti][tj]) =
          make_uint2(pk(acc[0], acc[1]), pk(acc[2], acc[3]));
    }
}

__device__ __forceinline__ void proxup(float (&x)[4][4],
                                       const float (&til)[4][4]) {
#pragma unroll
  for (int i = 0; i < 4; ++i)
#pragma unroll
    for (int j = 0; j < 4; ++j) {
      float ax = fabsf(til[i][j]) - 2e-5f;
      float nx = ax > 0.0f ? ax : 0.0f;
      x[i][j] = nx > 1.0f ? 1.0f : nx;
    }
}

// stage m = I + x.*x/64 into R-plane PR and T-plane PT (no barrier)
__device__ __forceinline__ void stage1(const float (&x)[4][4],
                                       u16* __restrict__ PR,
                                       u16* __restrict__ PT, const O& o,
                                       int r0, int c0) {
  float m[4][4];
#pragma unroll
  for (int i = 0; i < 4; ++i)
#pragma unroll
    for (int j = 0; j < 4; ++j)
      m[i][j] = fmaf(x[i][j] * x[i][j], 0.015625f,
                     (r0 + i == c0 + j) ? 1.0f : 0.0f);
#pragma unroll
  for (int i = 0; i < 4; ++i)
    *(uint2*)(PR + o.prow[i]) =
        make_uint2(pk(m[i][0], m[i][1]), pk(m[i][2], m[i][3]));
#pragma unroll
  for (int j = 0; j < 4; ++j)
    *(uint2*)(PT + o.pcol[j]) =
        make_uint2(pk(m[0][j], m[1][j]), pk(m[2][j], m[3][j]));
}

// gradient + prox; T63 in PT63, trace partials in red[0..3]
__device__ __forceinline__ void gradprox(float (&x)[4][4],
                                         const float (&sc)[4][4], float& alpha,
                                         const u16* __restrict__ PT63,
                                         const float* red, const O& o) {
  float tr = (red[0] + red[1]) + (red[2] + red[3]);
  alpha = fmaf(0.01f, tr * 0.015625f - 1.0f, alpha);
  const float a2 = alpha * 0.03125f;  // 2*alpha/64
  float til[4][4];
#pragma unroll
  for (int i = 0; i < 4; ++i) {
    uint2 w = *(const uint2*)(PT63 + o.prow[i]);
    float pt[4] = {rlo(w.x), rhi(w.x), rlo(w.y), rhi(w.y)};
#pragma unroll
    for (int j = 0; j < 4; ++j) {
      float g = fmaf(a2 * x[i][j], pt[j], -sc[i][j]);
      til[i][j] = fmaf(-0.01f, g, x[i][j]);
    }
  }
  proxup(x, til);
}

__global__ __launch_bounds__(256, 2) void dag_iter_kernel(
    const float* __restrict__ adj, float* __restrict__ out) {
  __shared__ __align__(16) u16 BUF[7 * PL];
  __shared__ float red[4];
  u16* S0 = BUF;
  u16* S1 = BUF + PL;
  u16* S2 = BUF + 2 * PL;
  u16* S3 = BUF + 3 * PL;
  u16* S4 = BUF + 4 * PL;
  u16* S5 = BUF + 5 * PL;
  u16* S6 = BUF + 6 * PL;

  // De-phase the two co-resident blocks (b and b+256 share a CU).
  if ((blockIdx.x >> 8) & 1) __builtin_amdgcn_s_sleep(11);

  const int tid = (int)threadIdx.x;
  const int lane = tid & 63;
  const int wv = tid >> 6;
  const int rh4 = (wv >> 1) << 1;
  const int ch4 = (wv & 1) << 1;
  const int l15 = lane & 15;
  const int grp = lane >> 4;
  const int l7 = l15 & 7;
  const int r0 = (tid & 15) << 2;
  const int c0 = (tid >> 4) << 2;

  O o;
#pragma unroll
  for (int q = 0; q < 2; ++q) {
    const int koff = (((q << 2) + grp) ^ l7) << 3;
#pragma unroll
    for (int t = 0; t < 2; ++t) {
      o.ra[t][q] = ((rh4 + t) * 16 + l15) * 64 + koff;
      o.rb[t][q] = ((ch4 + t) * 16 + l15) * 64 + koff;
    }
  }
#pragma unroll
  for (int ti = 0; ti < 2; ++ti)
#pragma unroll
    for (int tj = 0; tj < 2; ++tj) {
      const int a = rh4 + ti;
      const int b = ch4 + tj;
      o.sT[ti][tj] = (16 * b + l15) * 64 +
                     (((2 * a + (grp >> 1)) ^ l7) << 3) + ((grp & 1) << 2);
      o.sR[ti][tj] = (16 * a + l15) * 64 +
                     (((2 * b + (grp >> 1)) ^ l7) << 3) + ((grp & 1) << 2);
    }
#pragma unroll
  for (int i = 0; i < 4; ++i) {
    o.prow[i] =
        (r0 + i) * 64 + ((((c0 >> 3) ^ ((r0 + i) & 7))) << 3) + (c0 & 7);
    o.pcol[i] =
        (c0 + i) * 64 + ((((r0 >> 3) ^ ((c0 + i) & 7))) << 3) + (r0 & 7);
  }

  const float* src = adj + (size_t)blockIdx.x * 4096;
  float x[4][4], sc[4][4];
#pragma unroll
  for (int i = 0; i < 4; ++i) {
    f32x4 v = *(const f32x4*)(src + (r0 + i) * 64 + c0);
#pragma unroll
    for (int j = 0; j < 4; ++j) {
      x[i][j] = v[j];
      sc[i][j] = (v[j] > 0.5f) ? v[j] : 0.0f;
    }
  }
  float alpha = 0.0f;

  // ---- iteration 0: alpha == 0 -> grad = -scores; then stage ----
  {
    float til[4][4];
#pragma unroll
    for (int i = 0; i < 4; ++i)
#pragma unroll
      for (int j = 0; j < 4; ++j) til[i][j] = fmaf(0.01f, sc[i][j], x[i][j]);
    proxup(x, til);
    stage1(x, S0, S1, o, r0, c0);
    __syncthreads();
  }
  // ---- iterations 0..48: DAG t1..t6 ; iterations 1..49: gradprox ----
  for (int it = 0; it < 49; ++it) {
    {  // t1: m2 = m*m -> R2(S3), T2(S4)
      FR a = loadR(S0, o);
      FB b = loadT(S1, o);
      prodR(a, b, S3, o);
      prodT(a, b, S4, o);
      __syncthreads();
    }
    {  // t2: m3 = m2*m -> R3(S2); m4 = m2*m2 -> R4(S5), T4(S6)
      FR a2 = loadR(S3, o);
      FB bm = loadT(S1, o);
      FB b2 = loadT(S4, o);
      prodR(a2, bm, S2, o);
      prodR(a2, b2, S5, o);
      prodT(a2, b2, S6, o);
      __syncthreads();
    }
    {  // t3: m7 = m3*m4 -> R7(S0); m8 = m4*m4 -> R8(S3), T8(S4)
      FR a3 = loadR(S2, o);
      FR a4 = loadR(S5, o);
      FB b4 = loadT(S6, o);
      prodR(a3, b4, S0, o);
      prodR(a4, b4, S3, o);
      prodT(a4, b4, S4, o);
      __syncthreads();
    }
    {  // t4: m15 = m7*m8 -> R15(S1), T15(S2); m16 = m8*m8 -> R16(S5), T16(S6)
      FR a7 = loadR(S0, o);
      FR a8 = loadR(S3, o);
      FB b8 = loadT(S4, o);
      prodR(a7, b8, S1, o);
      prodT(a7, b8, S2, o);
      prodR(a8, b8, S5, o);
      prodT(a8, b8, S6, o);
      __syncthreads();
    }
    {  // t5: m31 = m15*m16 -> R31(S0); m32 = m16*m16 -> T32(S3);
       //     trace: tr(m30) = sum R15(S1) .* T15(S2) -> red
      FR a15 = loadR(S1, o);
      FR a16 = loadR(S5, o);
      FB b16 = loadT(S6, o);
      float part = 0.0f;
#pragma unroll
      for (int i = 0; i < 4; ++i) {
        uint2 a = *(const uint2*)(S1 + o.prow[i]);
        uint2 b = *(const uint2*)(S2 + o.prow[i]);
        part = fmaf(rlo(a.x), rlo(b.x), part);
        part = fmaf(rhi(a.x), rhi(b.x), part);
        part = fmaf(rlo(a.y), rlo(b.y), part);
        part = fmaf(rhi(a.y), rhi(b.y), part);
      }
#pragma unroll
      for (int off = 1; off < 64; off <<= 1) part += __shfl_xor(part, off);
      if (lane == 0) red[wv] = part;
      prodR(a15, b16, S0, o);
      prodT(a16, b16, S3, o);
      __syncthreads();
    }
    {  // t6: m63 = m31*m32 -> T63(S2)
      FR a31 = loadR(S0, o);
      FB b32 = loadT(S3, o);
      prodT(a31, b32, S2, o);
      __syncthreads();
    }
    // p0 of next iter: gradprox (T63 in S2, trace in red) + stage
    gradprox(x, sc, alpha, S2, red, o);
    if (it == 48) break;
    stage1(x, S0, S1, o, r0, c0);
    __syncthreads();
  }

  float* dst = out + (size_t)blockIdx.x * 4096;
#pragma unroll
  for (int i = 0; i < 4; ++i) {
    f32x4 v;
#pragma unroll
    for (int j = 0; j < 4; ++j) v[j] = (x[i][j] > 0.5f) ? x[i][j] : 0.0f;
    *(f32x4*)(dst + (r0 + i) * 64 + c0) = v;
  }
}

extern "C" void kernel_launch(void* const* d_in, const int* in_sizes, int n_in,
                              void* d_out, int out_size, void* d_ws,
                              size_t ws_size, hipStream_t stream) {
  const float* adj = (const float*)d_in[0];
  float* out = (float*)d_out;
  const int nbatch = in_sizes[0] / 4096;  // 512
  dag_iter_kernel<<<nbatch, 256, 0, stream>>>(adj, out);
}

// Round 13
// 261.291 us; speedup vs baseline: 2.7390x; 1.2258x over previous
//
#include <hip/hip_runtime.h>
#include <stdint.h>

// Each 64x64 matrix: bf16 planes in LDS, unpadded stride 64, XOR-swizzled:
//   element [r][c] at short-index  r*64 + (((c>>3) ^ (r&7))<<3) + (c&7)
//   R-plane: row-major (MFMA A-fragment = one b128)
//   T-plane: transposed (MFMA B-fragment = one b128)
// 6 fixed plane slots, 1-periodic schedule; all LDS addrs loop-invariant.
#define PL 4096  // shorts per plane

typedef unsigned int u32;
typedef unsigned short u16;
typedef float f32x4 __attribute__((ext_vector_type(4)));
typedef short short8 __attribute__((ext_vector_type(8)));

__device__ __forceinline__ u32 prm(u32 a, u32 b, u32 s) {
  return __builtin_amdgcn_perm(a, b, s);
}
__device__ __forceinline__ u32 pk(float f0, float f1) {  // {bf16 f0, bf16 f1}
  return prm(__float_as_uint(f1), __float_as_uint(f0), 0x07060302u);
}
__device__ __forceinline__ float rlo(u32 w) { return __uint_as_float(w << 16); }
__device__ __forceinline__ float rhi(u32 w) {
  return __uint_as_float(w & 0xffff0000u);
}

// Per-thread invariant LDS short-offsets (4-wave 2x2 quadrant split).
struct O {
  int ra[2][2];  // A-frag read [ti][q]
  int rb[2][2];  // B-frag read [tj][q]
  int sT[2][2];  // T-plane store for primary product tile (ti,tj)
  int sR[2][2];  // R-plane store for mirror product tile (ti,tj)
  int prow[4];   // patch addr: sidx(r0+i, c0), 4-elem run
  int pcol[4];   // patch addr: sidx(c0+j, r0), 4-elem run
};

// B-fragment register cache: the 4 b128 loads of one round's B-operand,
// reusable by any later round whose B-plane content is unchanged.
struct BF {
  short8 b0[2], b1[2];
};

__device__ __forceinline__ BF loadB(const u16* __restrict__ BT, const O& o) {
  BF f;
#pragma unroll
  for (int t = 0; t < 2; ++t) {
    f.b0[t] = *(const short8*)(BT + o.rb[t][0]);
    f.b1[t] = *(const short8*)(BT + o.rb[t][1]);
  }
  return f;
}

// C = A @ B (64x64 bf16). 4 waves, wave wv owns quadrant as 2x2 16x16 tiles.
// Primary (a x b) -> C^T-contiguous -> T-plane; mirror (b x a) -> R-plane.
// WR/WT gate dead planes. TR: diagonal waves (0,3) also compute sum R.*T of
// the loaded fragments (their a/b fragment index sets coincide element-for-
// element) = tr(A*B) -> tr(m30) for free when A=R15,B=T15.
// B-fragments come from a register cache. Dest planes != source planes.
// Trailing barrier.
template <bool WR, bool WT, bool TR = false>
__device__ __forceinline__ void mm_core(const u16* __restrict__ AR,
                                        const BF& bf, u16* __restrict__ CR,
                                        u16* __restrict__ CT, const O& o,
                                        float* red = nullptr) {
  short8 a0[2], a1[2];
#pragma unroll
  for (int t = 0; t < 2; ++t) {
    a0[t] = *(const short8*)(AR + o.ra[t][0]);
    a1[t] = *(const short8*)(AR + o.ra[t][1]);
  }
  if (TR) {
    const int tid = (int)threadIdx.x;
    const int wvv = tid >> 6;
    if (wvv == 0 || wvv == 3) {  // diagonal quadrants: frags element-aligned
      float part = 0.0f;
#pragma unroll
      for (int t = 0; t < 2; ++t) {
        const u32* ap0 = (const u32*)&a0[t];
        const u32* bp0 = (const u32*)&bf.b0[t];
        const u32* ap1 = (const u32*)&a1[t];
        const u32* bp1 = (const u32*)&bf.b1[t];
#pragma unroll
      for (int w = 0; w < 4; ++w) {
          part = fmaf(rlo(ap0[w]), rlo(bp0[w]), part);
          part = fmaf(rhi(ap0[w]), rhi(bp0[w]), part);
          part = fmaf(rlo(ap1[w]), rlo(bp1[w]), part);
          part = fmaf(rhi(ap1[w]), rhi(bp1[w]), part);
        }
      }
#pragma unroll
      for (int off = 1; off < 64; off <<= 1) part += __shfl_xor(part, off);
      if ((tid & 63) == 0) red[wvv == 0 ? 0 : 1] = part;
    }
  }
  const f32x4 Z = {0.0f, 0.0f, 0.0f, 0.0f};
#pragma unroll
  for (int ti = 0; ti < 2; ++ti)
#pragma unroll
    for (int tj = 0; tj < 2; ++tj) {
      if (WT) {
        f32x4 acc = __builtin_amdgcn_mfma_f32_16x16x32_bf16(a0[ti], bf.b0[tj],
                                                            Z, 0, 0, 0);
        acc = __builtin_amdgcn_mfma_f32_16x16x32_bf16(a1[ti], bf.b1[tj], acc,
                                                      0, 0, 0);
        *(uint2*)(CT + o.sT[ti][tj]) =
            make_uint2(pk(acc[0], acc[1]), pk(acc[2], acc[3]));
      }
      if (WR) {
        f32x4 acc = __builtin_amdgcn_mfma_f32_16x16x32_bf16(bf.b0[tj], a0[ti],
                                                            Z, 0, 0, 0);
        acc = __builtin_amdgcn_mfma_f32_16x16x32_bf16(bf.b1[tj], a1[ti], acc,
                                                      0, 0, 0);
        *(uint2*)(CR + o.sR[ti][tj]) =
            make_uint2(pk(acc[0], acc[1]), pk(acc[2], acc[3]));
      }
    }
  __syncthreads();
}

template <bool WR, bool WT, bool TR = false>
__device__ __forceinline__ void mm(const u16* __restrict__ AR,
                                   const u16* __restrict__ BT,
                                   u16* __restrict__ CR, u16* __restrict__ CT,
                                   const O& o, float* red = nullptr) {
  BF bf = loadB(BT, o);
  mm_core<WR, WT, TR>(AR, bf, CR, CT, o, red);
}

// One block (256 thr = 4 waves) per batch element; 2 blocks/CU. Thread owns a
// 4x4 patch (r0=(tid&15)*4, c0=(tid>>4)*4) for elementwise work.
//
// 1-periodic 6-slot schedule, invariant entering each iter:
//   PA=R15, PB=T15, PC=T3  (of current x)
//   f1 m30:(PA,PB)->(PD,PE) [+free trace into red]   f2 m60:(PD,PE)->PF [R]
//   f3 m63:(PF,cC=T3)->PD [T]
//   g: gradprox (alpha from red, T63 from PD); stage m(new x)->(PE=R, PF=T)
//   c1 m2:(PE,PF->cF)->PD [R]  c2 m3:(PD,cF)->(PE=R3, PC=T3)
//   c3 m6:(PE,PC->cC)->(PD,PF) c4 m12:(PD,PF)->PE [R]
//   c5 m15:(PE,cC)->(PA,PB)
// cC (T3) stays in registers from c3 through next iter's f3 (PC unchanged
// until the following c2); cF (T(m)) lives c1->c2 only.
__global__ __launch_bounds__(256, 2) void dag_iter_kernel(
    const float* __restrict__ adj, float* __restrict__ out) {
  __shared__ __align__(16) u16 BUF[6 * PL];
  __shared__ float red[2];
  u16* PA = BUF;
  u16* PB = BUF + PL;
  u16* PC = BUF + 2 * PL;
  u16* PD = BUF + 3 * PL;
  u16* PE = BUF + 4 * PL;
  u16* PF = BUF + 5 * PL;

  // De-phase the two co-resident blocks (b and b+256 share a CU): offset by
  // ~half a round so their LDS bursts interleave instead of colliding.
  if ((blockIdx.x >> 8) & 1) __builtin_amdgcn_s_sleep(11);

  const int tid = (int)threadIdx.x;
  const int lane = tid & 63;
  const int wv = tid >> 6;
  const int rh4 = (wv >> 1) << 1;
  const int ch4 = (wv & 1) << 1;
  const int l15 = lane & 15;
  const int grp = lane >> 4;
  const int l7 = l15 & 7;
  const int r0 = (tid & 15) << 2;
  const int c0 = (tid >> 4) << 2;

  O o;
#pragma unroll
  for (int q = 0; q < 2; ++q) {
    const int koff = (((q << 2) + grp) ^ l7) << 3;
#pragma unroll
    for (int t = 0; t < 2; ++t) {
      o.ra[t][q] = ((rh4 + t) * 16 + l15) * 64 + koff;
      o.rb[t][q] = ((ch4 + t) * 16 + l15) * 64 + koff;
    }
  }
#pragma unroll
  for (int ti = 0; ti < 2; ++ti)
#pragma unroll
    for (int tj = 0; tj < 2; ++tj) {
      const int a = rh4 + ti;
      const int b = ch4 + tj;
      o.sT[ti][tj] = (16 * b + l15) * 64 +
                     (((2 * a + (grp >> 1)) ^ l7) << 3) + ((grp & 1) << 2);
      o.sR[ti][tj] = (16 * a + l15) * 64 +
                     (((2 * b + (grp >> 1)) ^ l7) << 3) + ((grp & 1) << 2);
    }
#pragma unroll
  for (int i = 0; i < 4; ++i) {
    o.prow[i] =
        (r0 + i) * 64 + ((((c0 >> 3) ^ ((r0 + i) & 7))) << 3) + (c0 & 7);
    o.pcol[i] =
        (c0 + i) * 64 + ((((r0 >> 3) ^ ((c0 + i) & 7))) << 3) + (r0 & 7);
  }

  const float* src = adj + (size_t)blockIdx.x * 4096;
  float x[4][4], sc[4][4];
#pragma unroll
  for (int i = 0; i < 4; ++i) {
    f32x4 v = *(const f32x4*)(src + (r0 + i) * 64 + c0);
#pragma unroll
    for (int j = 0; j < 4; ++j) {
      x[i][j] = v[j];
      sc[i][j] = (v[j] > 0.5f) ? v[j] : 0.0f;
    }
  }
  float alpha = 0.0f;
  BF cC;  // register cache of T3's B-fragments (c3 -> c5 -> next f3)

  auto prox = [&](float til[4][4]) {
#pragma unroll
    for (int i = 0; i < 4; ++i)
#pragma unroll
      for (int j = 0; j < 4; ++j) {
        float ax = fabsf(til[i][j]) - 2e-5f;
        float nx = ax > 0.0f ? ax : 0.0f;
        x[i][j] = nx > 1.0f ? 1.0f : nx;
      }
  };
  auto stage = [&]() {  // m = I + x.*x/64 -> PE (R-plane), PF (T-plane)
    float m[4][4];
#pragma unroll
    for (int i = 0; i < 4; ++i)
#pragma unroll
      for (int j = 0; j < 4; ++j)
        m[i][j] = fmaf(x[i][j] * x[i][j], 0.015625f,
                       (r0 + i == c0 + j) ? 1.0f : 0.0f);
#pragma unroll
    for (int i = 0; i < 4; ++i)
      *(uint2*)(PE + o.prow[i]) =
          make_uint2(pk(m[i][0], m[i][1]), pk(m[i][2], m[i][3]));
#pragma unroll
    for (int j = 0; j < 4; ++j)
      *(uint2*)(PF + o.pcol[j]) =
          make_uint2(pk(m[0][j], m[1][j]), pk(m[2][j], m[3][j]));
    __syncthreads();
  };
  auto chain5 = [&]() {  // sources: PE=R(m), PF=T(m)
    BF cF = loadB(PF, o);                     // T(m), reused by c2
    mm_core<true, false>(PE, cF, PD, PD, o);  // c1: m2 -> R only
    mm_core<true, true>(PD, cF, PE, PC, o);   // c2: m3 -> (R3, T3)
    cC = loadB(PC, o);                        // T3, reused by c5 and next f3
    mm_core<true, true>(PE, cC, PD, PF, o);   // c3: m6 = m3^2
    mm<true, false>(PD, PF, PE, PE, o);       // c4: m12 -> R only
    mm_core<true, true>(PE, cC, PA, PB, o);   // c5: m15 -> (PA,PB)
  };
  auto gradprox = [&]() {  // alpha from red (tr(m30) of x_i); T63 in PD
    float tr = red[0] + red[1];
    alpha = fmaf(0.01f, tr * 0.015625f - 1.0f, alpha);
    const float a2 = alpha * 0.03125f;  // 2*alpha/64
    float til[4][4];
#pragma unroll
    for (int i = 0; i < 4; ++i) {
      uint2 w = *(const uint2*)(PD + o.prow[i]);
      float pt[4] = {rlo(w.x), rhi(w.x), rlo(w.y), rhi(w.y)};
#pragma unroll
      for (int j = 0; j < 4; ++j) {
        float g = fmaf(a2 * x[i][j], pt[j], -sc[i][j]);
        til[i][j] = fmaf(-0.01f, g, x[i][j]);
      }
    }
    prox(til);
  };
  auto front = [&]() {
    mm<true, true, true>(PA, PB, PD, PE, o, red);  // f1: m30 (+free trace)
    mm<true, false>(PD, PE, PF, PF, o);            // f2: m60 -> R only
    mm_core<false, true>(PF, cC, PD, PD, o);       // f3: m63 -> T only (PD)
  };

  // ---- iteration 0: alpha == 0 -> grad = -scores ----
  {
    float til[4][4];
#pragma unroll
    for (int i = 0; i < 4; ++i)
#pragma unroll
      for (int j = 0; j < 4; ++j) til[i][j] = fmaf(0.01f, sc[i][j], x[i][j]);
    prox(til);
    stage();
    chain5();
  }
  // ---- iterations 1..48 ----
  for (int it = 0; it < 48; ++it) {
    front();
    gradprox();
    stage();
    chain5();
  }
  // ---- iteration 49: no trailing stage/chain ----
  front();
  gradprox();

  float* dst = out + (size_t)blockIdx.x * 4096;
#pragma unroll
  for (int i = 0; i < 4; ++i) {
    f32x4 v;
#pragma unroll
    for (int j = 0; j < 4; ++j) v[j] = (x[i][j] > 0.5f) ? x[i][j] : 0.0f;
    *(f32x4*)(dst + (r0 + i) * 64 + c0) = v;
  }
}

extern "C" void kernel_launch(void* const* d_in, const int* in_sizes, int n_in,
                              void* d_out, int out_size, void* d_ws,
                              size_t ws_size, hipStream_t stream) {
  const float* adj = (const float*)d_in[0];
  float* out = (float*)d_out;
  const int nbatch = in_sizes[0] / 4096;  // 512
  dag_iter_kernel<<<nbatch, 256, 0, stream>>>(adj, out);
}